// Round 1
// baseline (500.783 us; speedup 1.0000x reference)
//
#include <hip/hip_runtime.h>

// ---------------- constants for this problem ----------------
// N_NODES=100000, N_EDGES=1600000, IN_FEATS=128, H=4, D=32, HD=128, NUM_ETYPES=8, DROP_BLOCKS=4

// K1: per-node etype histogram
__global__ void k_hist(const int* __restrict__ e_feat, const int* __restrict__ dst,
                       unsigned* __restrict__ cnt, int E) {
    int i = blockIdx.x * 256 + threadIdx.x;
    if (i < E) atomicAdd(&cnt[(unsigned)dst[i] * 8u + (unsigned)e_feat[i]], 1u);
}

// K2: per-node softmax stats: m[h], 1/s[h], deg
__global__ void k_stats(const unsigned* __restrict__ cnt, const float* __restrict__ emb,
                        float* __restrict__ stats, unsigned* __restrict__ deg, int N) {
    __shared__ float se[32];
    int t = threadIdx.x;
    if (t < 32) se[t] = emb[t];
    __syncthreads();
    int n = blockIdx.x * 256 + t;
    if (n >= N) return;
    uint4 a = *(const uint4*)(cnt + (size_t)n * 8);
    uint4 b = *(const uint4*)(cnt + (size_t)n * 8 + 4);
    unsigned c[8] = {a.x, a.y, a.z, a.w, b.x, b.y, b.z, b.w};
    unsigned dg = 0;
#pragma unroll
    for (int j = 0; j < 8; ++j) dg += c[j];
    deg[n] = dg;
#pragma unroll
    for (int h = 0; h < 4; ++h) {
        float m = -3.4e38f;
#pragma unroll
        for (int tt = 0; tt < 8; ++tt)
            if (c[tt]) m = fmaxf(m, se[tt * 4 + h]);
        float s = 0.f;
#pragma unroll
        for (int tt = 0; tt < 8; ++tt)
            if (c[tt]) s += (float)c[tt] * expf(se[tt * 4 + h] - m);
        stats[(size_t)n * 8 + h] = m;
        stats[(size_t)n * 8 + 4 + h] = dg ? (1.0f / s) : 0.0f;
    }
}

// K3a: per-block partial sums of deg
__global__ void k_scan_part(const unsigned* __restrict__ deg, unsigned* __restrict__ part, int N) {
    __shared__ unsigned s[256];
    int t = threadIdx.x;
    int n = blockIdx.x * 256 + t;
    s[t] = (n < N) ? deg[n] : 0u;
    __syncthreads();
    for (int of = 128; of > 0; of >>= 1) {
        if (t < of) s[t] += s[t + of];
        __syncthreads();
    }
    if (t == 0) part[blockIdx.x] = s[0];
}

// K3b: single-block exclusive scan of partials (NB <= 512)
__global__ void k_scan_block(const unsigned* __restrict__ part, unsigned* __restrict__ base, int NB) {
    __shared__ unsigned s[512];
    int t = threadIdx.x;
    s[t] = (t < NB) ? part[t] : 0u;
    __syncthreads();
    for (int of = 1; of < 512; of <<= 1) {
        unsigned v = (t >= of) ? s[t - of] : 0u;
        __syncthreads();
        s[t] += v;
        __syncthreads();
    }
    if (t < NB) base[t] = t ? s[t - 1] : 0u;
}

// K3c: per-node exclusive offsets
__global__ void k_scan_offs(const unsigned* __restrict__ deg, const unsigned* __restrict__ base,
                            unsigned* __restrict__ offs, int N) {
    __shared__ unsigned s[256];
    int t = threadIdx.x;
    int n = blockIdx.x * 256 + t;
    unsigned d = (n < N) ? deg[n] : 0u;
    s[t] = d;
    __syncthreads();
    for (int of = 1; of < 256; of <<= 1) {
        unsigned v = (t >= of) ? s[t - of] : 0u;
        __syncthreads();
        s[t] += v;
        __syncthreads();
    }
    if (n < N) offs[n] = base[blockIdx.x] + s[t] - d;
}

// K4a: scatter edges into CSR (packed src | etype<<20)
__global__ void k_scatter(const int* __restrict__ src, const int* __restrict__ dst,
                          const int* __restrict__ e_feat, const unsigned* __restrict__ offs,
                          unsigned* __restrict__ cursor, unsigned* __restrict__ csr, int E) {
    int e = blockIdx.x * 256 + threadIdx.x;
    if (e >= E) return;
    int d = dst[e];
    unsigned pos = offs[d] + atomicAdd(&cursor[d], 1u);
    csr[pos] = (unsigned)src[e] | ((unsigned)e_feat[e] << 20);
}

// K4b: attn_out (E, H, 4, 1) — value independent of block dim
__global__ void k_attn_out(const int* __restrict__ e_feat, const int* __restrict__ dst,
                           const float* __restrict__ emb, const float* __restrict__ stats,
                           float4* __restrict__ ao, int E4) {
    int i = blockIdx.x * 256 + threadIdx.x;
    if (i >= E4) return;
    int e = i >> 2, h = i & 3;
    int tt = e_feat[e];
    int d = dst[e];
    float a = expf(emb[tt * 4 + h] - stats[(size_t)d * 8 + h]) * stats[(size_t)d * 8 + 4 + h];
    ao[i] = make_float4(a, a, a, a);
}

// K5: ft = feat @ W^T   (fp32)
// block: 256 threads, 32 rows x 64 cols tile; W-tile in LDS [k][col] stride 68 (conflict-free)
__global__ __launch_bounds__(256) void k_gemm(const float* __restrict__ feat,
                                              const float* __restrict__ W,
                                              float* __restrict__ ft, int N) {
    __shared__ float Ws[128 * 68];
    int tid = threadIdx.x;
    int cb = blockIdx.y;          // 0 or 1: col tile of 64
    int rowbase = blockIdx.x * 32;
#pragma unroll
    for (int i = 0; i < 32; ++i) {
        int idx = i * 256 + tid;  // 0..8191
        int cl = idx >> 7;        // 0..63
        int k = idx & 127;
        Ws[k * 68 + cl] = W[(size_t)(cb * 64 + cl) * 128 + k];
    }
    __syncthreads();
    int col = tid & 63;
    int rg = tid >> 6;  // 0..3 -> 8 rows each
    float acc[8];
#pragma unroll
    for (int r = 0; r < 8; ++r) acc[r] = 0.f;
    const float* fp = feat + (size_t)(rowbase + rg * 8) * 128;
#pragma unroll 2
    for (int kc = 0; kc < 32; ++kc) {
        float w0 = Ws[(kc * 4 + 0) * 68 + col];
        float w1 = Ws[(kc * 4 + 1) * 68 + col];
        float w2 = Ws[(kc * 4 + 2) * 68 + col];
        float w3 = Ws[(kc * 4 + 3) * 68 + col];
#pragma unroll
        for (int r = 0; r < 8; ++r) {
            float4 f = *(const float4*)(fp + (size_t)r * 128 + kc * 4);
            acc[r] = fmaf(f.x, w0, acc[r]);
            acc[r] = fmaf(f.y, w1, acc[r]);
            acc[r] = fmaf(f.z, w2, acc[r]);
            acc[r] = fmaf(f.w, w3, acc[r]);
        }
    }
    float* op = ft + (size_t)(rowbase + rg * 8) * 128 + cb * 64 + col;
#pragma unroll
    for (int r = 0; r < 8; ++r) op[(size_t)r * 128] = acc[r];
}

// K6: aggregate: wave per node, float2 per lane, CSR walk
__global__ __launch_bounds__(256) void k_agg(const unsigned* __restrict__ csr,
                                             const unsigned* __restrict__ offs,
                                             const unsigned* __restrict__ deg,
                                             const float* __restrict__ stats,
                                             const float* __restrict__ emb,
                                             const float* __restrict__ ft,
                                             float* __restrict__ rst, int N) {
    __shared__ float wl[4 * 32];
    int tid = threadIdx.x;
    int wv = tid >> 6, lane = tid & 63;
    int n = blockIdx.x * 4 + wv;
    n = __builtin_amdgcn_readfirstlane(n);
    if (n < N && lane < 32) {
        int tt = lane >> 2, hh = lane & 3;
        float m = stats[(size_t)n * 8 + hh];
        float is = stats[(size_t)n * 8 + 4 + hh];
        wl[wv * 32 + lane] = expf(emb[tt * 4 + hh] - m) * is;
    }
    __syncthreads();
    if (n >= N) return;
    unsigned o = offs[n], dg = deg[n];
    int h = lane >> 4;
    float accx = 0.f, accy = 0.f;
    const float2* ft2 = (const float2*)ft;
    for (unsigned k = o; k < o + dg; ++k) {
        unsigned entry = csr[k];
        unsigned s = entry & 0xFFFFFu;
        unsigned tt = entry >> 20;
        float a = wl[wv * 32 + tt * 4 + h];
        float2 f = ft2[(size_t)s * 64 + lane];
        accx = fmaf(a, f.x, accx);
        accy = fmaf(a, f.y, accy);
    }
    float2 outv = make_float2(accx, accy);
    ((float2*)rst)[(size_t)n * 64 + lane] = outv;
}

extern "C" void kernel_launch(void* const* d_in, const int* in_sizes, int n_in,
                              void* d_out, int out_size, void* d_ws, size_t ws_size,
                              hipStream_t stream) {
    const float* feat = (const float*)d_in[0];
    const float* W = (const float*)d_in[1];
    const float* emb = (const float*)d_in[2];
    const int* e_feat = (const int*)d_in[3];
    const int* src = (const int*)d_in[4];
    const int* dst = (const int*)d_in[5];
    int N = in_sizes[0] / 128;
    int E = in_sizes[3];

    char* ws = (char*)d_ws;
    size_t off = 0;
    auto alloc = [&](size_t bytes) {
        void* p = ws + off;
        off = (off + bytes + 255) & ~(size_t)255;
        return p;
    };
    float* ft = (float*)alloc((size_t)N * 128 * 4);
    unsigned* cnt = (unsigned*)alloc((size_t)N * 8 * 4);
    unsigned* cursor = (unsigned*)alloc((size_t)N * 4);
    float* stats = (float*)alloc((size_t)N * 8 * 4);
    unsigned* deg = (unsigned*)alloc((size_t)N * 4);
    unsigned* offs = (unsigned*)alloc((size_t)N * 4);
    unsigned* csr = (unsigned*)alloc((size_t)E * 4);
    unsigned* part = (unsigned*)alloc(4096);
    unsigned* base = (unsigned*)alloc(4096);

    float* rst = (float*)d_out;
    float4* ao = (float4*)((float*)d_out + (size_t)N * 128);

    hipMemsetAsync(cnt, 0, (size_t)N * 8 * 4, stream);
    hipMemsetAsync(cursor, 0, (size_t)N * 4, stream);

    int NB = (N + 255) / 256;
    k_hist<<<(E + 255) / 256, 256, 0, stream>>>(e_feat, dst, cnt, E);
    k_stats<<<NB, 256, 0, stream>>>(cnt, emb, stats, deg, N);
    k_scan_part<<<NB, 256, 0, stream>>>(deg, part, N);
    k_scan_block<<<1, 512, 0, stream>>>(part, base, NB);
    k_scan_offs<<<NB, 256, 0, stream>>>(deg, base, offs, N);
    k_scatter<<<(E + 255) / 256, 256, 0, stream>>>(src, dst, e_feat, offs, cursor, csr, E);
    k_attn_out<<<(E * 4 + 255) / 256, 256, 0, stream>>>(e_feat, dst, emb, stats, ao, E * 4);
    dim3 ggrid((N + 31) / 32, 2);
    k_gemm<<<ggrid, 256, 0, stream>>>(feat, W, ft, N);
    k_agg<<<(N + 3) / 4, 256, 0, stream>>>(csr, offs, deg, stats, emb, ft, rst, N);
}

// Round 2
// 343.929 us; speedup vs baseline: 1.4561x; 1.4561x over previous
//
#include <hip/hip_runtime.h>

// ---------------- constants for this problem ----------------
// N_NODES=100000, N_EDGES=1600000, IN_FEATS=128, H=4, D=32, HD=128, NUM_ETYPES=8, DROP_BLOCKS=4

typedef short short8 __attribute__((ext_vector_type(8)));
typedef float f32x4 __attribute__((ext_vector_type(4)));

__device__ inline unsigned short f2bf(float x) {
    unsigned u = __builtin_bit_cast(unsigned, x);
    u += 0x7FFFu + ((u >> 16) & 1u);   // RNE
    return (unsigned short)(u >> 16);
}

// K1: per-node etype histogram
__global__ void k_hist(const int* __restrict__ e_feat, const int* __restrict__ dst,
                       unsigned* __restrict__ cnt, int E) {
    int i = blockIdx.x * 256 + threadIdx.x;
    if (i < E) atomicAdd(&cnt[(unsigned)dst[i] * 8u + (unsigned)e_feat[i]], 1u);
}

// K2: per-node softmax stats: m[h], 1/s[h], deg
__global__ void k_stats(const unsigned* __restrict__ cnt, const float* __restrict__ emb,
                        float* __restrict__ stats, unsigned* __restrict__ deg, int N) {
    __shared__ float se[32];
    int t = threadIdx.x;
    if (t < 32) se[t] = emb[t];
    __syncthreads();
    int n = blockIdx.x * 256 + t;
    if (n >= N) return;
    uint4 a = *(const uint4*)(cnt + (size_t)n * 8);
    uint4 b = *(const uint4*)(cnt + (size_t)n * 8 + 4);
    unsigned c[8] = {a.x, a.y, a.z, a.w, b.x, b.y, b.z, b.w};
    unsigned dg = 0;
#pragma unroll
    for (int j = 0; j < 8; ++j) dg += c[j];
    deg[n] = dg;
#pragma unroll
    for (int h = 0; h < 4; ++h) {
        float m = -3.4e38f;
#pragma unroll
        for (int tt = 0; tt < 8; ++tt)
            if (c[tt]) m = fmaxf(m, se[tt * 4 + h]);
        float s = 0.f;
#pragma unroll
        for (int tt = 0; tt < 8; ++tt)
            if (c[tt]) s += (float)c[tt] * expf(se[tt * 4 + h] - m);
        stats[(size_t)n * 8 + h] = m;
        stats[(size_t)n * 8 + 4 + h] = dg ? (1.0f / s) : 0.0f;
    }
}

// K3a: per-block partial sums of deg
__global__ void k_scan_part(const unsigned* __restrict__ deg, unsigned* __restrict__ part, int N) {
    __shared__ unsigned s[256];
    int t = threadIdx.x;
    int n = blockIdx.x * 256 + t;
    s[t] = (n < N) ? deg[n] : 0u;
    __syncthreads();
    for (int of = 128; of > 0; of >>= 1) {
        if (t < of) s[t] += s[t + of];
        __syncthreads();
    }
    if (t == 0) part[blockIdx.x] = s[0];
}

// K3b: single-block exclusive scan of partials (NB <= 512)
__global__ void k_scan_block(const unsigned* __restrict__ part, unsigned* __restrict__ base, int NB) {
    __shared__ unsigned s[512];
    int t = threadIdx.x;
    s[t] = (t < NB) ? part[t] : 0u;
    __syncthreads();
    for (int of = 1; of < 512; of <<= 1) {
        unsigned v = (t >= of) ? s[t - of] : 0u;
        __syncthreads();
        s[t] += v;
        __syncthreads();
    }
    if (t < NB) base[t] = t ? s[t - 1] : 0u;
}

// K3c: per-node exclusive offsets
__global__ void k_scan_offs(const unsigned* __restrict__ deg, const unsigned* __restrict__ base,
                            unsigned* __restrict__ offs, int N) {
    __shared__ unsigned s[256];
    int t = threadIdx.x;
    int n = blockIdx.x * 256 + t;
    unsigned d = (n < N) ? deg[n] : 0u;
    s[t] = d;
    __syncthreads();
    for (int of = 1; of < 256; of <<= 1) {
        unsigned v = (t >= of) ? s[t - of] : 0u;
        __syncthreads();
        s[t] += v;
        __syncthreads();
    }
    if (n < N) offs[n] = base[blockIdx.x] + s[t] - d;
}

// K4a: scatter edges into CSR (packed src | etype<<20)
__global__ void k_scatter(const int* __restrict__ src, const int* __restrict__ dst,
                          const int* __restrict__ e_feat, const unsigned* __restrict__ offs,
                          unsigned* __restrict__ cursor, unsigned* __restrict__ csr, int E) {
    int e = blockIdx.x * 256 + threadIdx.x;
    if (e >= E) return;
    int d = dst[e];
    unsigned pos = offs[d] + atomicAdd(&cursor[d], 1u);
    csr[pos] = (unsigned)src[e] | ((unsigned)e_feat[e] << 20);
}

// K4b: attn_out (E, H, 4, 1)
__global__ void k_attn_out(const int* __restrict__ e_feat, const int* __restrict__ dst,
                           const float* __restrict__ emb, const float* __restrict__ stats,
                           float4* __restrict__ ao, int E4) {
    int i = blockIdx.x * 256 + threadIdx.x;
    if (i >= E4) return;
    int e = i >> 2, h = i & 3;
    int tt = e_feat[e];
    int d = dst[e];
    float a = expf(emb[tt * 4 + h] - stats[(size_t)d * 8 + h]) * stats[(size_t)d * 8 + 4 + h];
    ao[i] = make_float4(a, a, a, a);
}

// K5: ft = feat @ W^T via bf16 MFMA.
// Block 256 = 4 waves; tile 128 rows x 128 cols, full K=128 in one staged pass.
// As[r][k], Bs[j][k] (=W row-major) bf16 in LDS, XOR-swizzled: byte ^= (row&7)<<4.
// Wave w computes rows [w*32, w*32+32) x all 128 cols: 2x8 tiles of 16x16, K-steps of 32.
__global__ __launch_bounds__(256) void k_gemm_mfma(const float* __restrict__ feat,
                                                   const float* __restrict__ W,
                                                   float* __restrict__ ft, int N) {
    __shared__ unsigned short As[128 * 128];  // 32 KB
    __shared__ unsigned short Bs[128 * 128];  // 32 KB
    int tid = threadIdx.x;
    int row0 = blockIdx.x * 128;

    // ---- stage: fp32 -> bf16, swizzled ----
#pragma unroll
    for (int it = 0; it < 16; ++it) {
        int i = it * 1024 + tid * 4;      // linear over 128x128
        int r = i >> 7, c = i & 127;
        unsigned swz = (unsigned)((r & 7) << 4);
        // B tile: W row-major IS Bs[j][k]
        float4 w4 = *(const float4*)(W + i);
        ushort4 wb;
        wb.x = f2bf(w4.x); wb.y = f2bf(w4.y); wb.z = f2bf(w4.z); wb.w = f2bf(w4.w);
        *(ushort4*)((char*)Bs + (((unsigned)(r * 256 + c * 2)) ^ swz)) = wb;
        // A tile: feat rows (guard)
        int gr = row0 + r;
        float4 a4 = make_float4(0.f, 0.f, 0.f, 0.f);
        if (gr < N) a4 = *(const float4*)(feat + (size_t)gr * 128 + c);
        ushort4 ab;
        ab.x = f2bf(a4.x); ab.y = f2bf(a4.y); ab.z = f2bf(a4.z); ab.w = f2bf(a4.w);
        *(ushort4*)((char*)As + (((unsigned)(r * 256 + c * 2)) ^ swz)) = ab;
    }
    __syncthreads();

    // ---- compute ----
    int wv = tid >> 6, lane = tid & 63;
    int rl = lane & 15;                 // row-within-tile / col-within-tile
    unsigned swz = (unsigned)((lane & 7) << 4);
    int kq = (lane >> 4) * 16;          // byte offset of this lane's k-octet

    f32x4 acc[2][8];
#pragma unroll
    for (int rt = 0; rt < 2; ++rt)
#pragma unroll
        for (int jt = 0; jt < 8; ++jt)
            acc[rt][jt] = (f32x4){0.f, 0.f, 0.f, 0.f};

    const char* Ab = (const char*)As;
    const char* Bb = (const char*)Bs;
#pragma unroll
    for (int kk = 0; kk < 4; ++kk) {
        int kb = kk * 64 + kq;
        short8 a[2], b[8];
        a[0] = *(const short8*)(Ab + (((unsigned)((wv * 32 + rl) * 256 + kb)) ^ swz));
        a[1] = *(const short8*)(Ab + (((unsigned)((wv * 32 + 16 + rl) * 256 + kb)) ^ swz));
#pragma unroll
        for (int jt = 0; jt < 8; ++jt)
            b[jt] = *(const short8*)(Bb + (((unsigned)((jt * 16 + rl) * 256 + kb)) ^ swz));
#pragma unroll
        for (int rt = 0; rt < 2; ++rt)
#pragma unroll
            for (int jt = 0; jt < 8; ++jt)
                acc[rt][jt] = __builtin_amdgcn_mfma_f32_16x16x32_bf16(a[rt], b[jt], acc[rt][jt], 0, 0, 0);
    }

    // ---- epilogue: D row=(lane>>4)*4+reg, col=lane&15 ----
#pragma unroll
    for (int rt = 0; rt < 2; ++rt) {
        int gr0 = row0 + wv * 32 + rt * 16 + ((lane >> 4) << 2);
#pragma unroll
        for (int jt = 0; jt < 8; ++jt) {
            int col = jt * 16 + rl;
#pragma unroll
            for (int rg = 0; rg < 4; ++rg) {
                int gr = gr0 + rg;
                if (gr < N) ft[(size_t)gr * 128 + col] = acc[rt][jt][rg];
            }
        }
    }
}

// K6: aggregate: wave per node, float2 per lane, CSR walk
__global__ __launch_bounds__(256) void k_agg(const unsigned* __restrict__ csr,
                                             const unsigned* __restrict__ offs,
                                             const unsigned* __restrict__ deg,
                                             const float* __restrict__ stats,
                                             const float* __restrict__ emb,
                                             const float* __restrict__ ft,
                                             float* __restrict__ rst, int N) {
    __shared__ float wl[4 * 32];
    int tid = threadIdx.x;
    int wv = tid >> 6, lane = tid & 63;
    int n = blockIdx.x * 4 + wv;
    n = __builtin_amdgcn_readfirstlane(n);
    if (n < N && lane < 32) {
        int tt = lane >> 2, hh = lane & 3;
        float m = stats[(size_t)n * 8 + hh];
        float is = stats[(size_t)n * 8 + 4 + hh];
        wl[wv * 32 + lane] = expf(emb[tt * 4 + hh] - m) * is;
    }
    __syncthreads();
    if (n >= N) return;
    unsigned o = offs[n], dg = deg[n];
    int h = lane >> 4;
    float accx = 0.f, accy = 0.f;
    const float2* ft2 = (const float2*)ft;
    for (unsigned k = o; k < o + dg; ++k) {
        unsigned entry = csr[k];
        unsigned s = entry & 0xFFFFFu;
        unsigned tt = entry >> 20;
        float a = wl[wv * 32 + tt * 4 + h];
        float2 f = ft2[(size_t)s * 64 + lane];
        accx = fmaf(a, f.x, accx);
        accy = fmaf(a, f.y, accy);
    }
    float2 outv = make_float2(accx, accy);
    ((float2*)rst)[(size_t)n * 64 + lane] = outv;
}

extern "C" void kernel_launch(void* const* d_in, const int* in_sizes, int n_in,
                              void* d_out, int out_size, void* d_ws, size_t ws_size,
                              hipStream_t stream) {
    const float* feat = (const float*)d_in[0];
    const float* W = (const float*)d_in[1];
    const float* emb = (const float*)d_in[2];
    const int* e_feat = (const int*)d_in[3];
    const int* src = (const int*)d_in[4];
    const int* dst = (const int*)d_in[5];
    int N = in_sizes[0] / 128;
    int E = in_sizes[3];

    char* ws = (char*)d_ws;
    size_t off = 0;
    auto alloc = [&](size_t bytes) {
        void* p = ws + off;
        off = (off + bytes + 255) & ~(size_t)255;
        return p;
    };
    float* ft = (float*)alloc((size_t)N * 128 * 4);
    unsigned* cnt = (unsigned*)alloc((size_t)N * 8 * 4);
    unsigned* cursor = (unsigned*)alloc((size_t)N * 4);
    float* stats = (float*)alloc((size_t)N * 8 * 4);
    unsigned* deg = (unsigned*)alloc((size_t)N * 4);
    unsigned* offs = (unsigned*)alloc((size_t)N * 4);
    unsigned* csr = (unsigned*)alloc((size_t)E * 4);
    unsigned* part = (unsigned*)alloc(4096);
    unsigned* base = (unsigned*)alloc(4096);

    float* rst = (float*)d_out;
    float4* ao = (float4*)((float*)d_out + (size_t)N * 128);

    hipMemsetAsync(cnt, 0, (size_t)N * 8 * 4, stream);
    hipMemsetAsync(cursor, 0, (size_t)N * 4, stream);

    int NB = (N + 255) / 256;
    k_hist<<<(E + 255) / 256, 256, 0, stream>>>(e_feat, dst, cnt, E);
    k_stats<<<NB, 256, 0, stream>>>(cnt, emb, stats, deg, N);
    k_scan_part<<<NB, 256, 0, stream>>>(deg, part, N);
    k_scan_block<<<1, 512, 0, stream>>>(part, base, NB);
    k_scan_offs<<<NB, 256, 0, stream>>>(deg, base, offs, N);
    k_scatter<<<(E + 255) / 256, 256, 0, stream>>>(src, dst, e_feat, offs, cursor, csr, E);
    k_attn_out<<<(E * 4 + 255) / 256, 256, 0, stream>>>(e_feat, dst, emb, stats, ao, E * 4);
    k_gemm_mfma<<<(N + 127) / 128, 256, 0, stream>>>(feat, W, ft, N);
    k_agg<<<(N + 3) / 4, 256, 0, stream>>>(csr, offs, deg, stats, emb, ft, rst, N);
}

// Round 3
// 292.394 us; speedup vs baseline: 1.7127x; 1.1763x over previous
//
#include <hip/hip_runtime.h>

// ---------------- constants for this problem ----------------
// N_NODES=100000, N_EDGES=1600000, IN_FEATS=128, H=4, D=32, HD=128, NUM_ETYPES=8, DROP_BLOCKS=4

typedef short short8 __attribute__((ext_vector_type(8)));
typedef float f32x4 __attribute__((ext_vector_type(4)));

__device__ inline unsigned short f2bf(float x) {
    unsigned u = __builtin_bit_cast(unsigned, x);
    u += 0x7FFFu + ((u >> 16) & 1u);   // RNE
    return (unsigned short)(u >> 16);
}

// K1: per-node etype histogram
__global__ void k_hist(const int* __restrict__ e_feat, const int* __restrict__ dst,
                       unsigned* __restrict__ cnt, int E) {
    int i = blockIdx.x * 256 + threadIdx.x;
    if (i < E) atomicAdd(&cnt[(unsigned)dst[i] * 8u + (unsigned)e_feat[i]], 1u);
}

// K2: per-node softmax stats: m[h], 1/s[h], deg
__global__ void k_stats(const unsigned* __restrict__ cnt, const float* __restrict__ emb,
                        float* __restrict__ stats, unsigned* __restrict__ deg, int N) {
    __shared__ float se[32];
    int t = threadIdx.x;
    if (t < 32) se[t] = emb[t];
    __syncthreads();
    int n = blockIdx.x * 256 + t;
    if (n >= N) return;
    uint4 a = *(const uint4*)(cnt + (size_t)n * 8);
    uint4 b = *(const uint4*)(cnt + (size_t)n * 8 + 4);
    unsigned c[8] = {a.x, a.y, a.z, a.w, b.x, b.y, b.z, b.w};
    unsigned dg = 0;
#pragma unroll
    for (int j = 0; j < 8; ++j) dg += c[j];
    deg[n] = dg;
#pragma unroll
    for (int h = 0; h < 4; ++h) {
        float m = -3.4e38f;
#pragma unroll
        for (int tt = 0; tt < 8; ++tt)
            if (c[tt]) m = fmaxf(m, se[tt * 4 + h]);
        float s = 0.f;
#pragma unroll
        for (int tt = 0; tt < 8; ++tt)
            if (c[tt]) s += (float)c[tt] * expf(se[tt * 4 + h] - m);
        stats[(size_t)n * 8 + h] = m;
        stats[(size_t)n * 8 + 4 + h] = dg ? (1.0f / s) : 0.0f;
    }
}

// K3a: per-block partial sums of deg
__global__ void k_scan_part(const unsigned* __restrict__ deg, unsigned* __restrict__ part, int N) {
    __shared__ unsigned s[256];
    int t = threadIdx.x;
    int n = blockIdx.x * 256 + t;
    s[t] = (n < N) ? deg[n] : 0u;
    __syncthreads();
    for (int of = 128; of > 0; of >>= 1) {
        if (t < of) s[t] += s[t + of];
        __syncthreads();
    }
    if (t == 0) part[blockIdx.x] = s[0];
}

// K3b: single-block exclusive scan of partials (NB <= 512)
__global__ void k_scan_block(const unsigned* __restrict__ part, unsigned* __restrict__ base, int NB) {
    __shared__ unsigned s[512];
    int t = threadIdx.x;
    s[t] = (t < NB) ? part[t] : 0u;
    __syncthreads();
    for (int of = 1; of < 512; of <<= 1) {
        unsigned v = (t >= of) ? s[t - of] : 0u;
        __syncthreads();
        s[t] += v;
        __syncthreads();
    }
    if (t < NB) base[t] = t ? s[t - 1] : 0u;
}

// K3c: per-node exclusive offsets
__global__ void k_scan_offs(const unsigned* __restrict__ deg, const unsigned* __restrict__ base,
                            unsigned* __restrict__ offs, int N) {
    __shared__ unsigned s[256];
    int t = threadIdx.x;
    int n = blockIdx.x * 256 + t;
    unsigned d = (n < N) ? deg[n] : 0u;
    s[t] = d;
    __syncthreads();
    for (int of = 1; of < 256; of <<= 1) {
        unsigned v = (t >= of) ? s[t - of] : 0u;
        __syncthreads();
        s[t] += v;
        __syncthreads();
    }
    if (n < N) offs[n] = base[blockIdx.x] + s[t] - d;
}

// K4a: scatter edges into CSR (packed src | etype<<20)
__global__ void k_scatter(const int* __restrict__ src, const int* __restrict__ dst,
                          const int* __restrict__ e_feat, const unsigned* __restrict__ offs,
                          unsigned* __restrict__ cursor, unsigned* __restrict__ csr, int E) {
    int e = blockIdx.x * 256 + threadIdx.x;
    if (e >= E) return;
    int d = dst[e];
    unsigned pos = offs[d] + atomicAdd(&cursor[d], 1u);
    csr[pos] = (unsigned)src[e] | ((unsigned)e_feat[e] << 20);
}

// K4b: attn_out (E, H, 4, 1)
__global__ void k_attn_out(const int* __restrict__ e_feat, const int* __restrict__ dst,
                           const float* __restrict__ emb, const float* __restrict__ stats,
                           float4* __restrict__ ao, int E4) {
    int i = blockIdx.x * 256 + threadIdx.x;
    if (i >= E4) return;
    int e = i >> 2, h = i & 3;
    int tt = e_feat[e];
    int d = dst[e];
    float a = expf(emb[tt * 4 + h] - stats[(size_t)d * 8 + h]) * stats[(size_t)d * 8 + 4 + h];
    ao[i] = make_float4(a, a, a, a);
}

// K5: ft = feat @ W^T via bf16 MFMA; output stored as bf16 for the gather.
__global__ __launch_bounds__(256) void k_gemm_mfma(const float* __restrict__ feat,
                                                   const float* __restrict__ W,
                                                   unsigned short* __restrict__ ftb, int N) {
    __shared__ unsigned short As[128 * 128];  // 32 KB
    __shared__ unsigned short Bs[128 * 128];  // 32 KB
    int tid = threadIdx.x;
    int row0 = blockIdx.x * 128;

    // ---- stage: fp32 -> bf16, swizzled (byte ^= (row&7)<<4) ----
#pragma unroll
    for (int it = 0; it < 16; ++it) {
        int i = it * 1024 + tid * 4;      // linear over 128x128
        int r = i >> 7, c = i & 127;
        unsigned swz = (unsigned)((r & 7) << 4);
        float4 w4 = *(const float4*)(W + i);
        ushort4 wb;
        wb.x = f2bf(w4.x); wb.y = f2bf(w4.y); wb.z = f2bf(w4.z); wb.w = f2bf(w4.w);
        *(ushort4*)((char*)Bs + (((unsigned)(r * 256 + c * 2)) ^ swz)) = wb;
        int gr = row0 + r;
        float4 a4 = make_float4(0.f, 0.f, 0.f, 0.f);
        if (gr < N) a4 = *(const float4*)(feat + (size_t)gr * 128 + c);
        ushort4 ab;
        ab.x = f2bf(a4.x); ab.y = f2bf(a4.y); ab.z = f2bf(a4.z); ab.w = f2bf(a4.w);
        *(ushort4*)((char*)As + (((unsigned)(r * 256 + c * 2)) ^ swz)) = ab;
    }
    __syncthreads();

    // ---- compute ----
    int wv = tid >> 6, lane = tid & 63;
    int rl = lane & 15;
    unsigned swz = (unsigned)((lane & 7) << 4);
    int kq = (lane >> 4) * 16;

    f32x4 acc[2][8];
#pragma unroll
    for (int rt = 0; rt < 2; ++rt)
#pragma unroll
        for (int jt = 0; jt < 8; ++jt)
            acc[rt][jt] = (f32x4){0.f, 0.f, 0.f, 0.f};

    const char* Ab = (const char*)As;
    const char* Bb = (const char*)Bs;
#pragma unroll
    for (int kk = 0; kk < 4; ++kk) {
        int kb = kk * 64 + kq;
        short8 a[2], b[8];
        a[0] = *(const short8*)(Ab + (((unsigned)((wv * 32 + rl) * 256 + kb)) ^ swz));
        a[1] = *(const short8*)(Ab + (((unsigned)((wv * 32 + 16 + rl) * 256 + kb)) ^ swz));
#pragma unroll
        for (int jt = 0; jt < 8; ++jt)
            b[jt] = *(const short8*)(Bb + (((unsigned)((jt * 16 + rl) * 256 + kb)) ^ swz));
#pragma unroll
        for (int rt = 0; rt < 2; ++rt)
#pragma unroll
            for (int jt = 0; jt < 8; ++jt)
                acc[rt][jt] = __builtin_amdgcn_mfma_f32_16x16x32_bf16(a[rt], b[jt], acc[rt][jt], 0, 0, 0);
    }

    // ---- epilogue: D row=(lane>>4)*4+reg, col=lane&15; write bf16 ----
#pragma unroll
    for (int rt = 0; rt < 2; ++rt) {
        int gr0 = row0 + wv * 32 + rt * 16 + ((lane >> 4) << 2);
#pragma unroll
        for (int jt = 0; jt < 8; ++jt) {
            int col = jt * 16 + rl;
#pragma unroll
            for (int rg = 0; rg < 4; ++rg) {
                int gr = gr0 + rg;
                if (gr < N) ftb[(size_t)gr * 128 + col] = f2bf(acc[rt][jt][rg]);
            }
        }
    }
}

// K6: aggregate: wave per node, bf16 ft rows (256 B), CSR walk unrolled x4
__global__ __launch_bounds__(256) void k_agg(const unsigned* __restrict__ csr,
                                             const unsigned* __restrict__ offs,
                                             const unsigned* __restrict__ deg,
                                             const float* __restrict__ stats,
                                             const float* __restrict__ emb,
                                             const unsigned* __restrict__ ftu,  // bf16 pairs
                                             float* __restrict__ rst, int N) {
    __shared__ float wl[4 * 32];
    int tid = threadIdx.x;
    int wv = tid >> 6, lane = tid & 63;
    int n = blockIdx.x * 4 + wv;
    n = __builtin_amdgcn_readfirstlane(n);
    if (n < N && lane < 32) {
        int tt = lane >> 2, hh = lane & 3;
        float m = stats[(size_t)n * 8 + hh];
        float is = stats[(size_t)n * 8 + 4 + hh];
        wl[wv * 32 + lane] = expf(emb[tt * 4 + hh] - m) * is;
    }
    __syncthreads();
    if (n >= N) return;
    unsigned o = offs[n], dg = deg[n];
    int h = lane >> 4;
    const float* wlh = wl + wv * 32 + h;
    float accx = 0.f, accy = 0.f;
    unsigned k = o, end = o + dg;
    for (; k + 4 <= end; k += 4) {
        unsigned c0 = csr[k], c1 = csr[k + 1], c2 = csr[k + 2], c3 = csr[k + 3];
        unsigned f0 = ftu[(size_t)(c0 & 0xFFFFFu) * 64 + lane];
        unsigned f1 = ftu[(size_t)(c1 & 0xFFFFFu) * 64 + lane];
        unsigned f2 = ftu[(size_t)(c2 & 0xFFFFFu) * 64 + lane];
        unsigned f3 = ftu[(size_t)(c3 & 0xFFFFFu) * 64 + lane];
        float a0 = wlh[(c0 >> 20) * 4];
        float a1 = wlh[(c1 >> 20) * 4];
        float a2 = wlh[(c2 >> 20) * 4];
        float a3 = wlh[(c3 >> 20) * 4];
        accx = fmaf(a0, __builtin_bit_cast(float, f0 << 16), accx);
        accy = fmaf(a0, __builtin_bit_cast(float, f0 & 0xFFFF0000u), accy);
        accx = fmaf(a1, __builtin_bit_cast(float, f1 << 16), accx);
        accy = fmaf(a1, __builtin_bit_cast(float, f1 & 0xFFFF0000u), accy);
        accx = fmaf(a2, __builtin_bit_cast(float, f2 << 16), accx);
        accy = fmaf(a2, __builtin_bit_cast(float, f2 & 0xFFFF0000u), accy);
        accx = fmaf(a3, __builtin_bit_cast(float, f3 << 16), accx);
        accy = fmaf(a3, __builtin_bit_cast(float, f3 & 0xFFFF0000u), accy);
    }
    for (; k < end; ++k) {
        unsigned c0 = csr[k];
        unsigned f0 = ftu[(size_t)(c0 & 0xFFFFFu) * 64 + lane];
        float a0 = wlh[(c0 >> 20) * 4];
        accx = fmaf(a0, __builtin_bit_cast(float, f0 << 16), accx);
        accy = fmaf(a0, __builtin_bit_cast(float, f0 & 0xFFFF0000u), accy);
    }
    ((float2*)rst)[(size_t)n * 64 + lane] = make_float2(accx, accy);
}

extern "C" void kernel_launch(void* const* d_in, const int* in_sizes, int n_in,
                              void* d_out, int out_size, void* d_ws, size_t ws_size,
                              hipStream_t stream) {
    const float* feat = (const float*)d_in[0];
    const float* W = (const float*)d_in[1];
    const float* emb = (const float*)d_in[2];
    const int* e_feat = (const int*)d_in[3];
    const int* src = (const int*)d_in[4];
    const int* dst = (const int*)d_in[5];
    int N = in_sizes[0] / 128;
    int E = in_sizes[3];

    char* ws = (char*)d_ws;
    size_t off = 0;
    auto alloc = [&](size_t bytes) {
        void* p = ws + off;
        off = (off + bytes + 255) & ~(size_t)255;
        return p;
    };
    unsigned short* ftb = (unsigned short*)alloc((size_t)N * 128 * 2);
    unsigned* cnt = (unsigned*)alloc((size_t)N * 8 * 4);
    unsigned* cursor = (unsigned*)alloc((size_t)N * 4);
    float* stats = (float*)alloc((size_t)N * 8 * 4);
    unsigned* deg = (unsigned*)alloc((size_t)N * 4);
    unsigned* offs = (unsigned*)alloc((size_t)N * 4);
    unsigned* csr = (unsigned*)alloc((size_t)E * 4);
    unsigned* part = (unsigned*)alloc(4096);
    unsigned* base = (unsigned*)alloc(4096);

    float* rst = (float*)d_out;
    float4* ao = (float4*)((float*)d_out + (size_t)N * 128);

    hipMemsetAsync(cnt, 0, (size_t)N * 8 * 4, stream);
    hipMemsetAsync(cursor, 0, (size_t)N * 4, stream);

    int NB = (N + 255) / 256;
    k_hist<<<(E + 255) / 256, 256, 0, stream>>>(e_feat, dst, cnt, E);
    k_stats<<<NB, 256, 0, stream>>>(cnt, emb, stats, deg, N);
    k_scan_part<<<NB, 256, 0, stream>>>(deg, part, N);
    k_scan_block<<<1, 512, 0, stream>>>(part, base, NB);
    k_scan_offs<<<NB, 256, 0, stream>>>(deg, base, offs, N);
    k_scatter<<<(E + 255) / 256, 256, 0, stream>>>(src, dst, e_feat, offs, cursor, csr, E);
    k_attn_out<<<(E * 4 + 255) / 256, 256, 0, stream>>>(e_feat, dst, emb, stats, ao, E * 4);
    k_gemm_mfma<<<(N + 127) / 128, 256, 0, stream>>>(feat, W, ftb, N);
    k_agg<<<(N + 3) / 4, 256, 0, stream>>>(csr, offs, deg, stats, emb, (const unsigned*)ftb, rst, N);
}